// Round 3
// baseline (144.516 us; speedup 1.0000x reference)
//
#include <hip/hip_runtime.h>

#define EPS 1e-5f

typedef float v2f __attribute__((ext_vector_type(2)));

constexpr int B = 32;
constexpr int H = 512;
constexpr int W = 512;
constexpr int NPIX = H * W;          // 262144
constexpr int P = 13;
constexpr int HP = H - P + 1;        // 500
constexpr int WP = W - P + 1;        // 500
constexpr int TILES_X = 8;           // 64 output cols per tile, 1 per lane
constexpr int BAND_OUT = 40;         // output rows per band
constexpr int BANDS_Y = 13;          // bands 0..11 -> rows 0..479; band 12 (y0=460) -> 480..499
constexpr int G = 13;                // ring depth == window height
constexpr int NROWS = 52;            // input rows per band; 460+52=512 exactly -> no row clamp
constexpr int NGROUPS = 4;           // 4 groups of 13 steps (ring indexing stays static)
constexpr int ITER_LAST_OWN = 20;    // band 12 owns rows 480..511 -> t >= 20
constexpr int ITER_LAST_EMIT = 32;   // band 12 emits rows 480..499 -> t >= 32
constexpr int BLOCKS_PER_B = TILES_X * BANDS_Y;  // 104
constexpr int RS = 76;               // LDS row stride: 64 cols + 12 halo = 76 = 19 lanes x 16B DMA

// direct global->LDS DMA, 16 B per active lane, dst = uniform base + lane*16
#define GLOAD_LDS16(gp, lp)                                                    \
  __builtin_amdgcn_global_load_lds(                                            \
      (const __attribute__((address_space(1))) unsigned int*)(const void*)(gp),\
      (__attribute__((address_space(3))) unsigned int*)(void*)(lp), 16, 0, 0)

// ---------------------------------------------------------------------------
// R9: rolling 13-row LDS ring, zero barriers, counted vmcnt (T4 pattern).
//  - R8 post-mortem: occupancy 10->18.5% and VALUBusy 15->25% but wall flat
//    (90->88us): occupancy gain canceled by 2x DS-traffic/output (read2_b32
//    per col vs b64 per 2 cols). Double-buffer is pure capacity waste: each
//    LDS row is read exactly once (its step), then dead.
//  - This round isolates ONE variable: LDS capacity. Ring of 13 row-slots,
//    slot u=t%13 (static via 13-unrolled group body, rule #20). One wave per
//    block -> no __syncthreads; DMA tracked by wave-level vmcnt:
//      prologue issues rows 0..12 (26 DMA instrs);
//      step t: s_waitcnt vmcnt(24)  [== "row t's 2 DMAs retired"; exactly 24
//              newer instrs exist at every step, held uniform by dummy
//              row-51 DMAs in the last group];
//              ds_read taps; s_waitcnt lgkmcnt(0); DMA row t+13 into slot u
//              (overwrite is safe: reads retired, DMA write lands ~900cyc
//              later); compute.
//      end: s_waitcnt vmcnt(0) so no straggler DMA writes a retired block's
//              reallocated LDS.
//  - LDS 15872 -> 7904 B: cap 20 blocks/CU; VGPR ~120-140 caps 12-16; work
//    is 13 blocks/CU -> fully resident. DS/VALU per step unchanged.
// grid = 32*8*13 = 3328 single-wave blocks; workspace 3328*6 floats = 78 KiB.
// ---------------------------------------------------------------------------
__global__ __launch_bounds__(64) void ncc_fused_kernel(
    const float* __restrict__ x1, const float* __restrict__ x2,
    float* __restrict__ part) {
  const int bid = blockIdx.x;
  const int b    = bid / BLOCKS_PER_B;
  const int rem  = bid % BLOCKS_PER_B;
  const int tile = rem % TILES_X;
  const int band = rem / TILES_X;
  const bool last = (band == BANDS_Y - 1);
  const int x0 = tile * 64;
  const int y0 = last ? (HP - BAND_OUT) : band * BAND_OUT;  // 460 for last band
  const int tid = threadIdx.x;
  const int c0 = x0 + tid;
  const bool valid = c0 < WP;

  __shared__ float sa[G][RS];   // 3952 B
  __shared__ float sb[G][RS];   // 3952 B  -> 7904 B total

  const float* r1 = x1 + (size_t)b * NPIX + (size_t)y0 * W + x0;
  const float* r2 = x2 + (size_t)b * NPIX + (size_t)y0 * W + x0;

  // loader: 19 lanes x float4 = 76 floats/row/plane. Tile 7 clamp: lanes
  // 16..18 re-read cols 508..511 into LDS floats 64..75, consumed only by
  // out-cols >= 500 (masked). DMA dst is lane-indexed: base + lane*16.
  int qoff = tid * 4;
  { int mx = W - x0 - 4; if (qoff > mx) qoff = mx; }
  const bool loader = tid < 19;

  // one band-relative row (2 DMA instrs, always issued: exec never 0)
  auto dma_row = [&](int row, int slot) {
    if (loader) {
      GLOAD_LDS16(r1 + (size_t)row * W + qoff, &sa[slot][0]);
      GLOAD_LDS16(r2 + (size_t)row * W + qoff, &sb[slot][0]);
    }
  };

  // prologue: rows 0..12 into slots 0..12 (26 DMA instrs in flight)
#pragma unroll
  for (int r = 0; r < G; ++r) dma_row(r, r);

  // vertical ring in registers, scalar per quantity (1 col per lane)
  float rr1[G], rr2[G], rr11[G], rr22[G], rr12[G];
  float S1 = 0.f, S2 = 0.f, S11 = 0.f, S22 = 0.f, S12 = 0.f;
  float g1 = 0.f, g2 = 0.f, g11 = 0.f, g22 = 0.f, g12 = 0.f;
  float acc = 0.f;
  const float inv_n = 1.0f / 169.0f;

  auto step = [&](int u, int t, bool fill) {
    // row t's 2 DMAs are the (25th,26th)-newest -> retired once <=24 remain
    asm volatile("s_waitcnt vmcnt(24)" ::: "memory");
    const float* pa = &sa[u][tid];
    const float* pb = &sb[u][tid];
    // taps 0..12; pairs (2j,2j+1) j=0..5 merge into ds_read2_b32, tap 12 b32
    v2f A2[6], B2[6];
#pragma unroll
    for (int j = 0; j < 6; ++j) {
      A2[j] = (v2f){pa[2 * j], pa[2 * j + 1]};
      B2[j] = (v2f){pb[2 * j], pb[2 * j + 1]};
    }
    float a12 = pa[12], b12 = pb[12];
    // taps retired -> safe to overwrite slot u with row t+13 (dummy 51 at tail
    // keeps the vmcnt(24) invariant uniform; slot never read again then)
    asm volatile("s_waitcnt lgkmcnt(0)" ::: "memory");
    {
      int nrow = t + G;
      if (nrow > NROWS - 1) nrow = NROWS - 1;
      dma_row(nrow, u);
    }

    v2f q11 = A2[0] * A2[0], q22 = B2[0] * B2[0], q12 = A2[0] * B2[0];
    v2f h1v = A2[0], h2v = B2[0], h11v = q11, h22v = q22, h12v = q12;
#pragma unroll
    for (int j = 1; j < 6; ++j) {
      h1v += A2[j];
      h2v += B2[j];
      h11v += A2[j] * A2[j];
      h22v += B2[j] * B2[j];
      h12v += A2[j] * B2[j];
    }
    float h1 = h1v.x + h1v.y + a12;
    float h2 = h2v.x + h2v.y + b12;
    float h11 = fmaf(a12, a12, h11v.x + h11v.y);
    float h22 = fmaf(b12, b12, h22v.x + h22v.y);
    float h12 = fmaf(a12, b12, h12v.x + h12v.y);

    // global moments: own col c0 = tap 0; squares reused from q*
    bool owned = last ? (t >= ITER_LAST_OWN) : (t < BAND_OUT);
    if (owned) {
      g1 += A2[0].x; g2 += B2[0].x;
      g11 += q11.x; g22 += q22.x; g12 += q12.x;
    }

    // vertical sliding sums via register ring
    if (fill) {
      S1 += h1; S2 += h2; S11 += h11; S22 += h22; S12 += h12;
    } else {
      S1 += h1 - rr1[u]; S2 += h2 - rr2[u];
      S11 += h11 - rr11[u]; S22 += h22 - rr22[u]; S12 += h12 - rr12[u];
    }
    rr1[u] = h1; rr2[u] = h2; rr11[u] = h11; rr22[u] = h22; rr12[u] = h12;

    // emit output row y0 + t - 12 (band 12 suppresses rows < 480)
    bool do_out = (t >= 12) && (!last || t >= ITER_LAST_EMIT);
    if (do_out) {
      float m1 = S1 * inv_n, m2 = S2 * inv_n;
      float vv1 = fmaf(-m1, m1, S11 * inv_n) + EPS;
      float vv2 = fmaf(-m2, m2, S22 * inv_n) + EPS;
      float cross = fmaf(-m1, S2, S12);
      float cc = cross * rsqrtf(vv1 * vv2);
      acc += valid ? cc : 0.f;
    }
  };

  // group 0: ring fill
#pragma unroll
  for (int u = 0; u < G; ++u) step(u, u, true);

  // groups 1..3: sliding (group loop dynamic, 13-step body unrolled so ring
  // and slot indices stay static — rule #20)
#pragma clang loop unroll(disable)
  for (int g = 1; g < NGROUPS; ++g) {
#pragma unroll
    for (int u = 0; u < G; ++u) step(u, g * G + u, false);
  }

  // drain all DMAs (incl. dummies) before this block's LDS can be reallocated
  asm volatile("s_waitcnt vmcnt(0)" ::: "memory");

  // wave-reduce 6 scalars, lane 0 writes block slot
  float v0 = acc;
  float w1 = g1, w2 = g2, w3 = g11, w4 = g22, w5 = g12;
#pragma unroll
  for (int off = 32; off > 0; off >>= 1) {
    v0 += __shfl_down(v0, off, 64);
    w1 += __shfl_down(w1, off, 64);
    w2 += __shfl_down(w2, off, 64);
    w3 += __shfl_down(w3, off, 64);
    w4 += __shfl_down(w4, off, 64);
    w5 += __shfl_down(w5, off, 64);
  }
  if (tid == 0) {
    float* o = part + (size_t)bid * 6;
    o[0] = v0; o[1] = w1; o[2] = w2; o[3] = w3; o[4] = w4; o[5] = w5;
  }
}

// ---------------------------------------------------------------------------
// Reduce per-block partials; one block per batch.
// out[b] = 0.5*global_ncc + 0.5*patch_sum/(HP*WP*169)
// ---------------------------------------------------------------------------
__global__ __launch_bounds__(64) void final_kernel(
    const float* __restrict__ part, float* __restrict__ out) {
  int b = blockIdx.x;
  int tid = threadIdx.x;
  float s[6] = {0.f, 0.f, 0.f, 0.f, 0.f, 0.f};
  for (int i = tid; i < BLOCKS_PER_B; i += 64) {
    const float* p = part + (size_t)(b * BLOCKS_PER_B + i) * 6;
#pragma unroll
    for (int k = 0; k < 6; ++k) s[k] += p[k];
  }
#pragma unroll
  for (int off = 32; off > 0; off >>= 1) {
#pragma unroll
    for (int k = 0; k < 6; ++k) s[k] += __shfl_down(s[k], off, 64);
  }
  if (tid == 0) {
    float Nf = (float)NPIX;
    float m1 = s[1] / Nf;
    float m2 = s[2] / Nf;
    float v1 = fmaf(-m1, m1, s[3] / Nf);
    float v2 = fmaf(-m2, m2, s[4] / Nf);
    float cross = fmaf(-Nf * m1, m2, s[5]);
    float g = cross * rsqrtf((v1 + EPS) * (v2 + EPS)) / Nf;
    float patch = s[0] / ((float)HP * (float)WP * 169.0f);
    out[b] = 0.5f * g + 0.5f * patch;
  }
}

extern "C" void kernel_launch(void* const* d_in, const int* in_sizes, int n_in,
                              void* d_out, int out_size, void* d_ws, size_t ws_size,
                              hipStream_t stream) {
  const float* x1 = (const float*)d_in[0];
  const float* x2 = (const float*)d_in[1];
  float* out = (float*)d_out;
  float* part = (float*)d_ws;   // 3328 * 6 floats = 78 KiB; every slot written

  ncc_fused_kernel<<<B * BLOCKS_PER_B, 64, 0, stream>>>(x1, x2, part);
  final_kernel<<<B, 64, 0, stream>>>(part, out);
}

// Round 4
// 113.054 us; speedup vs baseline: 1.2783x; 1.2783x over previous
//
#include <hip/hip_runtime.h>

#define EPS 1e-5f

typedef float v2f __attribute__((ext_vector_type(2)));

constexpr int B = 32;
constexpr int H = 512;
constexpr int W = 512;
constexpr int NPIX = H * W;          // 262144
constexpr int P = 13;
constexpr int HP = H - P + 1;        // 500
constexpr int WP = W - P + 1;        // 500
constexpr int TILE_W = 128;          // output cols per wave, 2 per lane
constexpr int TILES_X = 4;
constexpr int WAVES = 2;             // independent waves (tiles) per workgroup
constexpr int BAND_OUT = 40;         // output rows per band
constexpr int BANDS_Y = 13;          // bands 0..11 -> rows 0..479; band 12 (y0=460) -> 480..499
constexpr int G = 13;                // ring depth == window height
constexpr int NROWS = 52;            // input rows per band; 460+52=512 -> no row clamp
constexpr int NGROUPS = 4;           // 4 groups of 13 steps (static ring indices)
constexpr int ITER_LAST_OWN = 20;    // band 12 owns rows 480..511 -> t >= 20
constexpr int ITER_LAST_EMIT = 32;   // band 12 emits rows 480..499 -> t >= 32
constexpr int PAIRS_X = TILES_X / WAVES;        // 2 tile-pairs per band
constexpr int WGS_PER_B = PAIRS_X * BANDS_Y;    // 26 workgroups per batch
constexpr int UNITS_PER_B = TILES_X * BANDS_Y;  // 52 partial slots per batch
constexpr int RS = 140;              // LDS row stride: 128 cols + 12 halo (35 lanes x 16B DMA)

// direct global->LDS DMA, 16 B per active lane, dst = uniform base + lane*16
#define GLOAD_LDS16(gp, lp)                                                    \
  __builtin_amdgcn_global_load_lds(                                            \
      (const __attribute__((address_space(1))) unsigned int*)(const void*)(gp),\
      (__attribute__((address_space(3))) unsigned int*)(void*)(lp), 16, 0, 0)

#define WAITV24() asm volatile("s_waitcnt vmcnt(24)" ::: "memory")

// ---------------------------------------------------------------------------
// R10: dispatch-economy + instruction-economy, keeping the R9 ring.
//  - R9 post-mortem: per-block 40us->15.7us (ring removed barrier drains) but
//    residency collapsed to 2.8/CU. Little's law: 3328 wg / 73us = 45.6 wg/us
//    dispatch x 15.7us blocks = 716 resident = 2.8/CU exactly -> the kernel
//    became WORKGROUP-DISPATCH-RATE limited. Fix: 4x fewer, 2-wave wgs.
//  - 2 waves/wg, each wave an independent 128-wide tile: NO barriers (disjoint
//    LDS halves, per-wave vmcnt counters). grid 832 wg.
//  - 2 cols/lane (R6's proven step body, bit-exact): DS instrs/output halved
//    (7x b64 per plane per 2 cols), VALU/output ~1.8x down vs R9.
//  - R9 ring verbatim: 13-slot LDS ring, prologue 26 DMAs, per-step
//    vmcnt(24) -> ds_read taps -> lgkmcnt(0) -> DMA row t+13 (clamped; dummy
//    row-51 at tail keeps invariant) -> compute; end drain vmcnt(0).
//  - fill/slide unified: rr[] zero-init, always subtract -> single 13-step
//    body (~13KB code, I-cache safe; R9's 3-copy layout was ~25KB).
// Occupancy: LDS 29120 B -> 5 wg/CU; VGPR ~240 -> 8 waves/CU = 4 wg/CU;
// work 832/256 = 3.25 wg/CU -> fully resident, single generation.
// workspace: 1664 * 6 floats = 39 KiB; every slot written.
// ---------------------------------------------------------------------------
__global__ __launch_bounds__(128) void ncc_fused_kernel(
    const float* __restrict__ x1, const float* __restrict__ x2,
    float* __restrict__ part) {
  const int bid = blockIdx.x;
  const int b    = bid / WGS_PER_B;
  const int rem  = bid % WGS_PER_B;
  const int pair = rem % PAIRS_X;
  const int band = rem / PAIRS_X;
  const bool last = (band == BANDS_Y - 1);
  const int w    = threadIdx.x >> 6;   // wave id, uniform per wave
  const int lane = threadIdx.x & 63;
  const int tile = pair * WAVES + w;
  const int x0 = tile * TILE_W;
  const int y0 = last ? (HP - BAND_OUT) : band * BAND_OUT;  // 460 for last band
  const int c0 = x0 + 2 * lane;
  const bool valid0 = c0 < WP;
  const bool valid1 = (c0 + 1) < WP;

  __shared__ float sa[WAVES][G][RS];   // 2 x 7280 B
  __shared__ float sb[WAVES][G][RS];   // 2 x 7280 B  -> 29120 B total

  const float* r1 = x1 + (size_t)b * NPIX + (size_t)y0 * W + x0;
  const float* r2 = x2 + (size_t)b * NPIX + (size_t)y0 * W + x0;

  // loader: 35 lanes x float4 = 140 floats/row/plane. Tile 3 clamp: lanes
  // 31..34 re-read cols 508..511 into LDS floats 124..139, consumed only by
  // out-cols >= 500 (masked). DMA dst is wave-uniform base + lane*16.
  int qoff = lane * 4;
  { int mx = W - x0 - 4; if (qoff > mx) qoff = mx; }
  const bool loader = lane < 35;

  auto dma_row = [&](int row, int slot) {
    if (loader) {
      GLOAD_LDS16(r1 + (size_t)row * W + qoff, &sa[w][slot][0]);
      GLOAD_LDS16(r2 + (size_t)row * W + qoff, &sb[w][slot][0]);
    }
  };

  // prologue: rows 0..12 into slots 0..12 (26 DMA instrs in flight per wave)
#pragma unroll
  for (int r = 0; r < G; ++r) dma_row(r, r);

  // vertical ring in registers, v2f across the lane's 2 cols.
  // Zero-init -> fill steps are "slide minus zero": one unified step body.
  v2f rr1[G], rr2[G], rr11[G], rr22[G], rr12[G];
#pragma unroll
  for (int u = 0; u < G; ++u) {
    rr1[u] = (v2f){0.f, 0.f}; rr2[u] = (v2f){0.f, 0.f};
    rr11[u] = (v2f){0.f, 0.f}; rr22[u] = (v2f){0.f, 0.f};
    rr12[u] = (v2f){0.f, 0.f};
  }
  v2f S1 = {0.f, 0.f}, S2 = {0.f, 0.f}, S11 = {0.f, 0.f}, S22 = {0.f, 0.f},
      S12 = {0.f, 0.f};
  v2f g1 = {0.f, 0.f}, g2 = {0.f, 0.f}, g11 = {0.f, 0.f}, g22 = {0.f, 0.f},
      g12 = {0.f, 0.f};
  float acc = 0.f;
  const float inv_n = 1.0f / 169.0f;

  auto step = [&](int u, int t) {
    const float* pa = &sa[w][u][2 * lane];
    const float* pb = &sb[w][u][2 * lane];
    v2f A[7], Bv[7];
#pragma unroll
    for (int k = 0; k < 7; ++k) {
      A[k] = *(const v2f*)(pa + 2 * k);   // 8B-aligned ds_read_b64
      Bv[k] = *(const v2f*)(pb + 2 * k);
    }
    // taps retired -> safe to overwrite slot u with row t+13 (dummy row 51 at
    // tail keeps the vmcnt(24) invariant; that slot is never read again)
    asm volatile("s_waitcnt lgkmcnt(0)" ::: "memory");
    {
      int nrow = t + G;
      if (nrow > NROWS - 1) nrow = NROWS - 1;
      dma_row(nrow, u);
    }

    // c0 window = floats 0..12; c1 window = floats 1..13 (A[6].y is tap 13)
    v2f q11 = A[0] * A[0], q22 = Bv[0] * Bv[0], q12 = A[0] * Bv[0];
    v2f h1v = A[0], h2v = Bv[0], h11v = q11, h22v = q22, h12v = q12;
#pragma unroll
    for (int k = 1; k < 6; ++k) {
      h1v += A[k];
      h2v += Bv[k];
      h11v += A[k] * A[k];
      h22v += Bv[k] * Bv[k];
      h12v += A[k] * Bv[k];
    }
    float a12 = A[6].x, b12 = Bv[6].x, a13 = A[6].y, b13 = Bv[6].y;
    float h1_0 = h1v.x + h1v.y + a12;
    float h2_0 = h2v.x + h2v.y + b12;
    float h11_0 = fmaf(a12, a12, h11v.x + h11v.y);
    float h22_0 = fmaf(b12, b12, h22v.x + h22v.y);
    float h12_0 = fmaf(a12, b12, h12v.x + h12v.y);
    // incremental shift for c1
    v2f h1 = {h1_0, h1_0 - A[0].x + a13};
    v2f h2 = {h2_0, h2_0 - Bv[0].x + b13};
    v2f h11 = {h11_0, fmaf(a13, a13, h11_0 - q11.x)};
    v2f h22 = {h22_0, fmaf(b13, b13, h22_0 - q22.x)};
    v2f h12 = {h12_0, fmaf(a13, b13, h12_0 - q12.x)};

    // global moments: own cols (c0,c1) = A[0]/Bv[0] as v2f; squares reused
    bool owned = last ? (t >= ITER_LAST_OWN) : (t < BAND_OUT);
    if (owned) {
      g1 += A[0]; g2 += Bv[0]; g11 += q11; g22 += q22; g12 += q12;
    }

    // vertical sliding sums via register ring (rr starts at 0 -> fill == slide)
    S1 += h1 - rr1[u]; S2 += h2 - rr2[u];
    S11 += h11 - rr11[u]; S22 += h22 - rr22[u]; S12 += h12 - rr12[u];
    rr1[u] = h1; rr2[u] = h2; rr11[u] = h11; rr22[u] = h22; rr12[u] = h12;

    // emit output row y0 + t - 12 (band 12 suppresses rows < 480)
    bool do_out = (t >= 12) && (!last || t >= ITER_LAST_EMIT);
    if (do_out) {
      v2f m1 = S1 * inv_n, m2 = S2 * inv_n;
      v2f vv1 = S11 * inv_n - m1 * m1 + EPS;
      v2f vv2 = S22 * inv_n - m2 * m2 + EPS;
      v2f cross = S12 - (S1 * inv_n) * S2;
      v2f den = vv1 * vv2;
      float cc0 = cross.x * rsqrtf(den.x);
      float cc1 = cross.y * rsqrtf(den.y);
      acc += (valid0 ? cc0 : 0.f) + (valid1 ? cc1 : 0.f);
    }
  };

  // 52 steps: dynamic group loop, 13-step unrolled body (static ring indices).
  // Per step: row t's 2 DMAs are the (25th,26th)-newest -> retired at vmcnt<=24.
#pragma clang loop unroll(disable)
  for (int g = 0; g < NGROUPS; ++g) {
#pragma unroll
    for (int u = 0; u < G; ++u) {
      WAITV24();
      step(u, g * G + u);
    }
  }

  // drain all DMAs (incl. dummies) before this block's LDS can be reallocated
  asm volatile("s_waitcnt vmcnt(0)" ::: "memory");

  // fold v2f col-pairs, wave-reduce 6 scalars, lane 0 of each wave writes slot
  float v0 = acc;
  float w1 = g1.x + g1.y, w2 = g2.x + g2.y;
  float w3 = g11.x + g11.y, w4 = g22.x + g22.y, w5 = g12.x + g12.y;
#pragma unroll
  for (int off = 32; off > 0; off >>= 1) {
    v0 += __shfl_down(v0, off, 64);
    w1 += __shfl_down(w1, off, 64);
    w2 += __shfl_down(w2, off, 64);
    w3 += __shfl_down(w3, off, 64);
    w4 += __shfl_down(w4, off, 64);
    w5 += __shfl_down(w5, off, 64);
  }
  if (lane == 0) {
    // uid = b*52 + rem*2 + w : contiguous per batch
    float* o = part + (size_t)(bid * WAVES + w) * 6;
    o[0] = v0; o[1] = w1; o[2] = w2; o[3] = w3; o[4] = w4; o[5] = w5;
  }
}

// ---------------------------------------------------------------------------
// Reduce per-unit partials; one block per batch.
// out[b] = 0.5*global_ncc + 0.5*patch_sum/(HP*WP*169)
// ---------------------------------------------------------------------------
__global__ __launch_bounds__(64) void final_kernel(
    const float* __restrict__ part, float* __restrict__ out) {
  int b = blockIdx.x;
  int tid = threadIdx.x;
  float s[6] = {0.f, 0.f, 0.f, 0.f, 0.f, 0.f};
  for (int i = tid; i < UNITS_PER_B; i += 64) {
    const float* p = part + (size_t)(b * UNITS_PER_B + i) * 6;
#pragma unroll
    for (int k = 0; k < 6; ++k) s[k] += p[k];
  }
#pragma unroll
  for (int off = 32; off > 0; off >>= 1) {
#pragma unroll
    for (int k = 0; k < 6; ++k) s[k] += __shfl_down(s[k], off, 64);
  }
  if (tid == 0) {
    float Nf = (float)NPIX;
    float m1 = s[1] / Nf;
    float m2 = s[2] / Nf;
    float v1 = fmaf(-m1, m1, s[3] / Nf);
    float v2 = fmaf(-m2, m2, s[4] / Nf);
    float cross = fmaf(-Nf * m1, m2, s[5]);
    float g = cross * rsqrtf((v1 + EPS) * (v2 + EPS)) / Nf;
    float patch = s[0] / ((float)HP * (float)WP * 169.0f);
    out[b] = 0.5f * g + 0.5f * patch;
  }
}

extern "C" void kernel_launch(void* const* d_in, const int* in_sizes, int n_in,
                              void* d_out, int out_size, void* d_ws, size_t ws_size,
                              hipStream_t stream) {
  const float* x1 = (const float*)d_in[0];
  const float* x2 = (const float*)d_in[1];
  float* out = (float*)d_out;
  float* part = (float*)d_ws;   // 1664 * 6 floats = 39 KiB; every slot written

  ncc_fused_kernel<<<B * WGS_PER_B, WAVES * 64, 0, stream>>>(x1, x2, part);
  final_kernel<<<B, 64, 0, stream>>>(part, out);
}

// Round 5
// 108.410 us; speedup vs baseline: 1.3330x; 1.0428x over previous
//
#include <hip/hip_runtime.h>

#define EPS 1e-5f

typedef float v2f __attribute__((ext_vector_type(2)));

constexpr int B = 32;
constexpr int H = 512;
constexpr int W = 512;
constexpr int NPIX = H * W;          // 262144
constexpr int P = 13;
constexpr int HP = H - P + 1;        // 500
constexpr int WP = W - P + 1;        // 500
constexpr int TILE_W = 128;          // output cols per wave, 2 per lane
constexpr int TILES_X = 4;
constexpr int WAVES = 2;             // independent waves (tiles) per workgroup
constexpr int BAND_OUT = 33;         // output rows per band
constexpr int BANDS_Y = 16;          // 15*33=495<500<=16*33; last band y0=467
constexpr int G = 13;                // ring depth == window height
constexpr int NROWS = 45;            // staged rows per band = 33+12; 467+45=512 -> no row clamp
constexpr int NGROUPS = 3;           // 3 x 13-step groups + 6-step tail = 45
constexpr int TAIL = NROWS - NGROUPS * G;        // 6
constexpr int ITER_LAST_OWN = 28;    // band 15 owns input rows 495..511 -> t >= 28 (467+28=495)
constexpr int ITER_LAST_EMIT = 40;   // band 15 emits out rows 495..499 -> t >= 40 (467+40-12=495)
constexpr int PAIRS_X = TILES_X / WAVES;        // 2 tile-pairs per band
constexpr int WGS_PER_B = PAIRS_X * BANDS_Y;    // 32 workgroups per batch
constexpr int UNITS_PER_B = TILES_X * BANDS_Y;  // 64 partial slots per batch
constexpr int RS = 140;              // LDS row stride: 128 cols + 12 halo (35 lanes x 16B DMA)

// direct global->LDS DMA, 16 B per active lane, dst = uniform base + lane*16
#define GLOAD_LDS16(gp, lp)                                                    \
  __builtin_amdgcn_global_load_lds(                                            \
      (const __attribute__((address_space(1))) unsigned int*)(const void*)(gp),\
      (__attribute__((address_space(3))) unsigned int*)(void*)(lp), 16, 0, 0)

#define WAITV24() asm volatile("s_waitcnt vmcnt(24)" ::: "memory")

// ---------------------------------------------------------------------------
// R11: perfect grid balance + deeper co-residency + per-step deserialization.
//  - R10 post-mortem: dur 127.6->113.1 (best); all ncc dispatches now <41.5us
//    (below the harness's 256MiB workspace-poison fill) -> counters blind,
//    dur_us is the instrument.
//  - Remaining structure: 832 wg = 3.25/CU (64 CUs run 4 wg, 192 run 3 ->
//    wall set by the 4-wg CUs) and only 1.6 waves/SIMD of work vs the
//    2/SIMD VGPR cap. Per-step lgkmcnt(0) drained ALL 28 tap loads before
//    any compute (DMA was issued pre-compute) — pure serialization.
//  - Fix 1: BAND_OUT 33, BANDS 16 -> grid 32*2*16 = 1024 wg = EXACTLY 4/CU,
//    fully resident single generation, 8 waves/CU (VGPR cap). Blocks 45
//    steps (was 52). Fetch 720 rows vs 676 (+6.5%, free at 8% HBM util).
//    Ownership: bands 0..14 own input rows [33k,33k+33) (t<33); band 15
//    (y0=467) owns t>=28 (rows 495..511). Emission: bands 0..14 emit
//    t in [12,45) (out rows 33k..33k+32); band 15 emits t>=40 (495..499).
//  - Fix 2: DMA issued AFTER compute: taps -> compute (compiler emits
//    fine-grained lgkmcnt(N), overlapping load latency with the adds) ->
//    lgkmcnt(0) (already ~0) -> DMA row t+13 into freed slot. vmcnt(24)
//    invariant unchanged (26 outstanding steady; dummy row-44 DMAs at tail).
//  - 45 = 3*13 + 6: dynamic group loop over 13-step unrolled body + static
//    6-step tail (ring/slot indices compile-time, rule #20).
// Occupancy: LDS 29120 B -> 5 wg/CU; VGPR ~240 -> 4 wg/CU (binding); work
// 1024/256 = 4/CU exact. workspace: 2048 * 6 floats = 48 KiB.
// ---------------------------------------------------------------------------
__global__ __launch_bounds__(128) void ncc_fused_kernel(
    const float* __restrict__ x1, const float* __restrict__ x2,
    float* __restrict__ part) {
  const int bid = blockIdx.x;
  const int b    = bid / WGS_PER_B;
  const int rem  = bid % WGS_PER_B;
  const int pair = rem % PAIRS_X;
  const int band = rem / PAIRS_X;
  const bool last = (band == BANDS_Y - 1);
  const int w    = threadIdx.x >> 6;   // wave id, uniform per wave
  const int lane = threadIdx.x & 63;
  const int tile = pair * WAVES + w;
  const int x0 = tile * TILE_W;
  const int y0 = last ? (HP - BAND_OUT) : band * BAND_OUT;  // 467 for last band
  const int c0 = x0 + 2 * lane;
  const bool valid0 = c0 < WP;
  const bool valid1 = (c0 + 1) < WP;

  __shared__ float sa[WAVES][G][RS];   // 2 x 7280 B
  __shared__ float sb[WAVES][G][RS];   // 2 x 7280 B  -> 29120 B total

  const float* r1 = x1 + (size_t)b * NPIX + (size_t)y0 * W + x0;
  const float* r2 = x2 + (size_t)b * NPIX + (size_t)y0 * W + x0;

  // loader: 35 lanes x float4 = 140 floats/row/plane. Tile 3 clamp: lanes
  // 32..34 re-read cols 508..511 into LDS floats 128..139, consumed only by
  // out-cols >= 500 (masked). DMA dst is wave-uniform base + lane*16.
  int qoff = lane * 4;
  { int mx = W - x0 - 4; if (qoff > mx) qoff = mx; }
  const bool loader = lane < 35;

  auto dma_row = [&](int row, int slot) {
    if (loader) {
      GLOAD_LDS16(r1 + (size_t)row * W + qoff, &sa[w][slot][0]);
      GLOAD_LDS16(r2 + (size_t)row * W + qoff, &sb[w][slot][0]);
    }
  };

  // prologue: rows 0..12 into slots 0..12 (26 DMA instrs in flight per wave)
#pragma unroll
  for (int r = 0; r < G; ++r) dma_row(r, r);

  // vertical ring in registers, v2f across the lane's 2 cols.
  // Zero-init -> fill steps are "slide minus zero": one unified step body.
  v2f rr1[G], rr2[G], rr11[G], rr22[G], rr12[G];
#pragma unroll
  for (int u = 0; u < G; ++u) {
    rr1[u] = (v2f){0.f, 0.f}; rr2[u] = (v2f){0.f, 0.f};
    rr11[u] = (v2f){0.f, 0.f}; rr22[u] = (v2f){0.f, 0.f};
    rr12[u] = (v2f){0.f, 0.f};
  }
  v2f S1 = {0.f, 0.f}, S2 = {0.f, 0.f}, S11 = {0.f, 0.f}, S22 = {0.f, 0.f},
      S12 = {0.f, 0.f};
  v2f g1 = {0.f, 0.f}, g2 = {0.f, 0.f}, g11 = {0.f, 0.f}, g22 = {0.f, 0.f},
      g12 = {0.f, 0.f};
  float acc = 0.f;
  const float inv_n = 1.0f / 169.0f;

  auto step = [&](int u, int t) {
    const float* pa = &sa[w][u][2 * lane];
    const float* pb = &sb[w][u][2 * lane];
    v2f A[7], Bv[7];
#pragma unroll
    for (int k = 0; k < 7; ++k) {
      A[k] = *(const v2f*)(pa + 2 * k);   // 8B-aligned ds_read_b64
      Bv[k] = *(const v2f*)(pb + 2 * k);
    }

    // c0 window = floats 0..12; c1 window = floats 1..13 (A[6].y is tap 13)
    v2f q11 = A[0] * A[0], q22 = Bv[0] * Bv[0], q12 = A[0] * Bv[0];
    v2f h1v = A[0], h2v = Bv[0], h11v = q11, h22v = q22, h12v = q12;
#pragma unroll
    for (int k = 1; k < 6; ++k) {
      h1v += A[k];
      h2v += Bv[k];
      h11v += A[k] * A[k];
      h22v += Bv[k] * Bv[k];
      h12v += A[k] * Bv[k];
    }
    float a12 = A[6].x, b12 = Bv[6].x, a13 = A[6].y, b13 = Bv[6].y;
    float h1_0 = h1v.x + h1v.y + a12;
    float h2_0 = h2v.x + h2v.y + b12;
    float h11_0 = fmaf(a12, a12, h11v.x + h11v.y);
    float h22_0 = fmaf(b12, b12, h22v.x + h22v.y);
    float h12_0 = fmaf(a12, b12, h12v.x + h12v.y);
    // incremental shift for c1
    v2f h1 = {h1_0, h1_0 - A[0].x + a13};
    v2f h2 = {h2_0, h2_0 - Bv[0].x + b13};
    v2f h11 = {h11_0, fmaf(a13, a13, h11_0 - q11.x)};
    v2f h22 = {h22_0, fmaf(b13, b13, h22_0 - q22.x)};
    v2f h12 = {h12_0, fmaf(a13, b13, h12_0 - q12.x)};

    // global moments: own cols (c0,c1) = A[0]/Bv[0] as v2f; squares reused
    bool owned = last ? (t >= ITER_LAST_OWN) : (t < BAND_OUT);
    if (owned) {
      g1 += A[0]; g2 += Bv[0]; g11 += q11; g22 += q22; g12 += q12;
    }

    // vertical sliding sums via register ring (rr starts at 0 -> fill == slide)
    S1 += h1 - rr1[u]; S2 += h2 - rr2[u];
    S11 += h11 - rr11[u]; S22 += h22 - rr22[u]; S12 += h12 - rr12[u];
    rr1[u] = h1; rr2[u] = h2; rr11[u] = h11; rr22[u] = h22; rr12[u] = h12;

    // emit output row y0 + t - 12 (band 15 suppresses rows < 495)
    bool do_out = (t >= 12) && (!last || t >= ITER_LAST_EMIT);
    if (do_out) {
      v2f m1 = S1 * inv_n, m2 = S2 * inv_n;
      v2f vv1 = S11 * inv_n - m1 * m1 + EPS;
      v2f vv2 = S22 * inv_n - m2 * m2 + EPS;
      v2f cross = S12 - (S1 * inv_n) * S2;
      v2f den = vv1 * vv2;
      float cc0 = cross.x * rsqrtf(den.x);
      float cc1 = cross.y * rsqrtf(den.y);
      acc += (valid0 ? cc0 : 0.f) + (valid1 ? cc1 : 0.f);
    }

    // taps consumed by compute (compiler-inserted lgkmcnt) -> slot u free.
    // Drain any stragglers, then DMA row t+13 into it (clamped: dummy row-44
    // DMAs at the tail keep the vmcnt(24) invariant; never read again).
    asm volatile("s_waitcnt lgkmcnt(0)" ::: "memory");
    {
      int nrow = t + G;
      if (nrow > NROWS - 1) nrow = NROWS - 1;
      dma_row(nrow, u);
    }
  };

  // 45 steps: 3 x 13-step groups (dynamic loop, static ring indices) + 6 tail.
  // Per step: row t's 2 DMAs are the (25th,26th)-newest -> retired at vmcnt<=24.
#pragma clang loop unroll(disable)
  for (int g = 0; g < NGROUPS; ++g) {
#pragma unroll
    for (int u = 0; u < G; ++u) {
      WAITV24();
      step(u, g * G + u);
    }
  }
#pragma unroll
  for (int u = 0; u < TAIL; ++u) {
    WAITV24();
    step(u, NGROUPS * G + u);
  }

  // drain all DMAs (incl. dummies) before this block's LDS can be reallocated
  asm volatile("s_waitcnt vmcnt(0)" ::: "memory");

  // fold v2f col-pairs, wave-reduce 6 scalars, lane 0 of each wave writes slot
  float v0 = acc;
  float w1 = g1.x + g1.y, w2 = g2.x + g2.y;
  float w3 = g11.x + g11.y, w4 = g22.x + g22.y, w5 = g12.x + g12.y;
#pragma unroll
  for (int off = 32; off > 0; off >>= 1) {
    v0 += __shfl_down(v0, off, 64);
    w1 += __shfl_down(w1, off, 64);
    w2 += __shfl_down(w2, off, 64);
    w3 += __shfl_down(w3, off, 64);
    w4 += __shfl_down(w4, off, 64);
    w5 += __shfl_down(w5, off, 64);
  }
  if (lane == 0) {
    // uid = b*64 + rem*2 + w : contiguous per batch
    float* o = part + (size_t)(bid * WAVES + w) * 6;
    o[0] = v0; o[1] = w1; o[2] = w2; o[3] = w3; o[4] = w4; o[5] = w5;
  }
}

// ---------------------------------------------------------------------------
// Reduce per-unit partials; one block per batch (64 units -> one per thread).
// out[b] = 0.5*global_ncc + 0.5*patch_sum/(HP*WP*169)
// ---------------------------------------------------------------------------
__global__ __launch_bounds__(64) void final_kernel(
    const float* __restrict__ part, float* __restrict__ out) {
  int b = blockIdx.x;
  int tid = threadIdx.x;
  float s[6] = {0.f, 0.f, 0.f, 0.f, 0.f, 0.f};
  for (int i = tid; i < UNITS_PER_B; i += 64) {
    const float* p = part + (size_t)(b * UNITS_PER_B + i) * 6;
#pragma unroll
    for (int k = 0; k < 6; ++k) s[k] += p[k];
  }
#pragma unroll
  for (int off = 32; off > 0; off >>= 1) {
#pragma unroll
    for (int k = 0; k < 6; ++k) s[k] += __shfl_down(s[k], off, 64);
  }
  if (tid == 0) {
    float Nf = (float)NPIX;
    float m1 = s[1] / Nf;
    float m2 = s[2] / Nf;
    float v1 = fmaf(-m1, m1, s[3] / Nf);
    float v2 = fmaf(-m2, m2, s[4] / Nf);
    float cross = fmaf(-Nf * m1, m2, s[5]);
    float g = cross * rsqrtf((v1 + EPS) * (v2 + EPS)) / Nf;
    float patch = s[0] / ((float)HP * (float)WP * 169.0f);
    out[b] = 0.5f * g + 0.5f * patch;
  }
}

extern "C" void kernel_launch(void* const* d_in, const int* in_sizes, int n_in,
                              void* d_out, int out_size, void* d_ws, size_t ws_size,
                              hipStream_t stream) {
  const float* x1 = (const float*)d_in[0];
  const float* x2 = (const float*)d_in[1];
  float* out = (float*)d_out;
  float* part = (float*)d_ws;   // 2048 * 6 floats = 48 KiB; every slot written

  ncc_fused_kernel<<<B * WGS_PER_B, WAVES * 64, 0, stream>>>(x1, x2, part);
  final_kernel<<<B, 64, 0, stream>>>(part, out);
}